// Round 2
// baseline (1028.004 us; speedup 1.0000x reference)
//
#include <hip/hip_runtime.h>
#include <math.h>

#define NPTS 4096
#define NB 16
#define NS 1024
#define KNB 32
#define CPTS 64

// ---- ws byte layout ----
#define FLAG_OFF_B  0          // 16 x u32 flags
#define CNT_OFF_B   64         // u32 work counter
#define PUBC_OFF_B  128        // fp32 pubC[16][1024][3]
#define WFRAG_ELEMS 18432
#define NUNITS      16384      // 16 batches x 1024 queries, one query per wave
#define CAP         256        // candidate buffer per wave (E[cnt]~44)
#define GRAB        8          // units per work-steal atomic

typedef __attribute__((ext_vector_type(8))) short short8;
typedef __attribute__((ext_vector_type(4))) float f32x4;

__device__ __forceinline__ short f2bf(float f) {   // RNE fp32->bf16
  unsigned u = __float_as_uint(f);
  unsigned r = (u + 0x7fffu + ((u >> 16) & 1u)) >> 16;
  return (short)r;
}

// ---------------- DPP helpers (FPS phase) ----------------
template <int CTRL>
__device__ __forceinline__ int dppmov(int cur) {
  return __builtin_amdgcn_update_dpp(cur, cur, CTRL, 0xF, 0xF, false);
}
template <int CTRL>
__device__ __forceinline__ void dpp_max_u64(unsigned& hi, unsigned& lo) {
  unsigned nhi = (unsigned)dppmov<CTRL>((int)hi);
  unsigned nlo = (unsigned)dppmov<CTRL>((int)lo);
  bool gt = (nhi > hi) || (nhi == hi && nlo > lo);
  hi = gt ? nhi : hi;
  lo = gt ? nlo : lo;
}
template <int CTRL>
__device__ __forceinline__ void dpp_fmax(float& m) {
  m = fmaxf(m, __int_as_float(dppmov<CTRL>(__float_as_int(m))));
}
template <int CTRL>
__device__ __forceinline__ void dpp_umin(unsigned& v) {
  unsigned o = (unsigned)dppmov<CTRL>((int)v);
  v = (o < v) ? o : v;
}

#define XSTR 104
__global__ __launch_bounds__(512, 2) void fused_kernel(
    const float* __restrict__ xyz, const float* __restrict__ points,
    const float* __restrict__ w0, const float* __restrict__ cb0, const float* __restrict__ g0,
    const float* __restrict__ b0, const float* __restrict__ m0, const float* __restrict__ v0,
    const float* __restrict__ w1, const float* __restrict__ cb1, const float* __restrict__ g1,
    const float* __restrict__ b1, const float* __restrict__ m1, const float* __restrict__ v1,
    const float* __restrict__ w2, const float* __restrict__ cb2, const float* __restrict__ g2,
    const float* __restrict__ b2, const float* __restrict__ m2, const float* __restrict__ v2,
    char* __restrict__ wsb, float* __restrict__ newxyz, float* __restrict__ outp) {
  struct FpsSh {
    float4 sxyz4[NPTS];                       // 64 KB
    float4 centL[NS];                         // 16 KB
    unsigned long long part[2][8];
  };
  struct WorkerSh {
    short Wlds[WFRAG_ELEMS];                  // 36 KB
    short X[8][32 * XSTR];                    // 52 KB (per-wave MLP tile)
    unsigned long long cand[8][CAP];          // 16 KB (per-wave knn candidates)
    int nnL[8][KNB];                          // 1 KB
    float biasL[256];                         // 1 KB
    unsigned cnt[8];
  };
  __shared__ union { FpsSh f; WorkerSh w; } sh;

  const int t = threadIdx.x;
  const int lane = t & 63;
  const int wave = t >> 6;
  unsigned* flagp = (unsigned*)(wsb + FLAG_OFF_B);
  unsigned* cntp  = (unsigned*)(wsb + CNT_OFF_B);
  float* pubC = (float*)(wsb + PUBC_OFF_B);

  if (blockIdx.x < NB) {
    // ================= FPS (verified r10 config: 8 waves x 8 pts; slot-read DPP merge) ====
    const int b = blockIdx.x;
    const float* xb = xyz + (size_t)b * NPTS * 3;
    float* outb = newxyz + (size_t)b * NS * 3;

    for (int i = t; i < NPTS; i += 512)
      sh.f.sxyz4[i] = make_float4(xb[i * 3 + 0], xb[i * 3 + 1], xb[i * 3 + 2], 0.f);

    float px[8], py[8], pz[8], dist[8];
#pragma unroll
    for (int j = 0; j < 8; ++j) {
      int n = t + 512 * j;
      px[j] = xb[n * 3 + 0];
      py[j] = xb[n * 3 + 1];
      pz[j] = xb[n * 3 + 2];
      dist[j] = 1e10f;
    }
    __syncthreads();
    float cx = sh.f.sxyz4[0].x, cy = sh.f.sxyz4[0].y, cz = sh.f.sxyz4[0].z;
    if (t == 0) sh.f.centL[0] = sh.f.sxyz4[0];

    for (int it = 1; it < NS; ++it) {
      const int buf = it & 1;
      float dm[8];
#pragma unroll
      for (int j = 0; j < 8; ++j) {
        // exact replication of sum((xyz - c)**2, -1): no FMA contraction
        float dx = __fsub_rn(px[j], cx);
        float dy = __fsub_rn(py[j], cy);
        float dz = __fsub_rn(pz[j], cz);
        float d  = __fadd_rn(__fadd_rn(__fmul_rn(dx, dx), __fmul_rn(dy, dy)), __fmul_rn(dz, dz));
        float v  = fminf(dist[j], d);
        dist[j] = v;
        dm[j] = v;
      }
      // lane max (7-instr tree), then 6-stage f32 DPP max -> lane 63
      float m = fmaxf(fmaxf(fmaxf(dm[0], dm[1]), fmaxf(dm[2], dm[3])),
                      fmaxf(fmaxf(dm[4], dm[5]), fmaxf(dm[6], dm[7])));
      dpp_fmax<0xB1>(m);  dpp_fmax<0x4E>(m);  dpp_fmax<0x141>(m);
      dpp_fmax<0x140>(m); dpp_fmax<0x142>(m); dpp_fmax<0x143>(m);
      float M = __int_as_float(__builtin_amdgcn_readlane(__float_as_int(m), 63));
      // min index with dm == M: parallel select + min tree (idx monotone in j ->
      // same lowest-index result as the old serial overwrite chain)
      unsigned i0 = (dm[0] == M) ? (unsigned)(t + 512 * 0) : 0xFFFFFFFFu;
      unsigned i1 = (dm[1] == M) ? (unsigned)(t + 512 * 1) : 0xFFFFFFFFu;
      unsigned i2 = (dm[2] == M) ? (unsigned)(t + 512 * 2) : 0xFFFFFFFFu;
      unsigned i3 = (dm[3] == M) ? (unsigned)(t + 512 * 3) : 0xFFFFFFFFu;
      unsigned i4 = (dm[4] == M) ? (unsigned)(t + 512 * 4) : 0xFFFFFFFFu;
      unsigned i5 = (dm[5] == M) ? (unsigned)(t + 512 * 5) : 0xFFFFFFFFu;
      unsigned i6 = (dm[6] == M) ? (unsigned)(t + 512 * 6) : 0xFFFFFFFFu;
      unsigned i7 = (dm[7] == M) ? (unsigned)(t + 512 * 7) : 0xFFFFFFFFu;
      unsigned a01 = i0 < i1 ? i0 : i1, a23 = i2 < i3 ? i2 : i3;
      unsigned a45 = i4 < i5 ? i4 : i5, a67 = i6 < i7 ? i6 : i7;
      unsigned a03 = a01 < a23 ? a01 : a23, a47 = a45 < a67 ? a45 : a67;
      unsigned idxl = a03 < a47 ? a03 : a47;
      dpp_umin<0xB1>(idxl);  dpp_umin<0x4E>(idxl);  dpp_umin<0x141>(idxl);
      dpp_umin<0x140>(idxl); dpp_umin<0x142>(idxl); dpp_umin<0x143>(idxl);
      if (lane == 63)
        sh.f.part[buf][wave] = ((unsigned long long)__float_as_uint(M) << 32) | (unsigned)(~idxl);
      __syncthreads();
      // merge 8 wave partials: slot read + 3-stage DPP u64 max (every lane gets winner)
      unsigned long long k0 = sh.f.part[buf][lane & 7];
      unsigned khi = (unsigned)(k0 >> 32), klo = (unsigned)k0;
      dpp_max_u64<0xB1>(khi, klo);    // xor1
      dpp_max_u64<0x4E>(khi, klo);    // xor2
      dpp_max_u64<0x141>(khi, klo);   // half-mirror: combines the two 4-groups
      int bi = (int)(~klo) & 4095;
      float4 c4 = sh.f.sxyz4[bi];
      cx = c4.x; cy = c4.y; cz = c4.z;
      if (t == 0) sh.f.centL[it] = c4;
      // publish: drain prior chunk's pubC stores (long done), relaxed flag store
      // (no cache-maintenance), then store this chunk's centroids (bypassing).
      if ((it & 31) == 31 && wave == 0) {
        if (lane == 0) {
          asm volatile("s_waitcnt vmcnt(0)" ::: "memory");
          __hip_atomic_store(&flagp[b], (unsigned)(it - 31), __ATOMIC_RELAXED, __HIP_MEMORY_SCOPE_AGENT);
        }
        if (lane < 32) {
          int ci = it - 31 + lane;
          float4 cc = sh.f.centL[ci];
          float* dst = pubC + ((size_t)b * NS + ci) * 3;
          __hip_atomic_store(dst + 0, cc.x, __ATOMIC_RELAXED, __HIP_MEMORY_SCOPE_AGENT);
          __hip_atomic_store(dst + 1, cc.y, __ATOMIC_RELAXED, __HIP_MEMORY_SCOPE_AGENT);
          __hip_atomic_store(dst + 2, cc.z, __ATOMIC_RELAXED, __HIP_MEMORY_SCOPE_AGENT);
        }
      }
    }
    // final flag (drain last chunk's stores once)
    if (wave == 0 && lane == 0) {
      asm volatile("s_waitcnt vmcnt(0)" ::: "memory");
      __hip_atomic_store(&flagp[b], (unsigned)NS, __ATOMIC_RELAXED, __HIP_MEMORY_SCOPE_AGENT);
    }
    __syncthreads();
    const float* cf = (const float*)sh.f.centL;
    for (int i = t; i < NS * 3; i += 512) {
      int p = i / 3, c = i - p * 3;
      outb[i] = cf[p * 4 + c];
    }
  }

  // ================= worker phase =================
  // One query per WAVE; GRAB units per steal. All polls RELAXED + per-wave
  // lane-indexed flag cache (lane i caches flag[i]) -> ~zero poll traffic.
  __syncthreads();
  // BN-folded bf16 weight fragments + biases into LDS.
  // K-column permutation for layer 0: X cols 0..63 = points[0..63] (w0 k'=c+3),
  // cols 64..66 = xyz_norm (w0 k'=c-64), cols 67..95 = zero weights.
  for (int i = t; i < WFRAG_ELEMS; i += 512) {
    int g = i >> 9, ln = (i >> 3) & 63, j = i & 7;
    int l, nt, s;
    if (g < 12)      { l = 0; nt = g / 3;  s = g % 3; }
    else if (g < 20) { l = 1; int gg = g - 12; nt = gg >> 1; s = gg & 1; }
    else             { l = 2; int gg = g - 20; nt = gg >> 1; s = gg & 1; }
    int n = nt * 16 + (ln & 15);
    int k = s * 32 + ((ln >> 4) << 3) + j;
    float val = 0.f;
    if (l == 0) {
      float sc = g0[n] / sqrtf(v0[n] + 1e-5f);
      if (k < 64)      val = w0[n * 67 + (k + 3)] * sc;
      else if (k < 67) val = w0[n * 67 + (k - 64)] * sc;
    }
    else if (l == 1) { val = w1[n * 64 + k] * (g1[n] / sqrtf(v1[n] + 1e-5f)); }
    else { val = w2[n * 64 + k] * (g2[n] / sqrtf(v2[n] + 1e-5f)); }
    sh.w.Wlds[i] = f2bf(val);
  }
  if (t < 256) {
    int o = t;
    float bv;
    if (o < 64)       { float sc = g0[o] / sqrtf(v0[o] + 1e-5f); bv = (cb0[o] - m0[o]) * sc + b0[o]; }
    else if (o < 128) { int c = o - 64;  float sc = g1[c] / sqrtf(v1[c] + 1e-5f); bv = (cb1[c] - m1[c]) * sc + b1[c]; }
    else              { int c = o - 128; float sc = g2[c] / sqrtf(v2[c] + 1e-5f); bv = (cb2[c] - m2[c]) * sc + b2[c]; }
    sh.w.biasL[o] = bv;
  }
  __syncthreads();   // weights/bias visible to all waves before any wave starts

  unsigned long long* cand = sh.w.cand[wave];
  // one-time zero of this wave's X tile (cols 67..95 stay zero; zero-weight cols
  // must not read uninitialized LDS that could encode NaN/Inf)
  for (int i = lane; i < (32 * XSTR) / 2; i += 64) ((int*)sh.w.X[wave])[i] = 0;

  unsigned fcache = 0;   // lane i holds last-seen flag[i] (i<16)

  for (;;) {
    unsigned base = 0;
    if (lane == 0) base = atomicAdd(cntp, (unsigned)GRAB);
    base = (unsigned)__builtin_amdgcn_readfirstlane((int)base);
    if (base >= NUNITS) break;
    unsigned uend = base + GRAB;
    if (uend > NUNITS) uend = NUNITS;

    for (unsigned u = base; u < uend; ++u) {
    const int b = (int)(u & 15u);
    const int s = (int)(u >> 4);

    // producer wait: cached-flag fast path, relaxed polls otherwise
    {
      unsigned need = (unsigned)s + 1u;
      unsigned have = (unsigned)__shfl((int)fcache, b, 64);
      if (have < need) {
        unsigned f;
        for (;;) {
          f = __hip_atomic_load(&flagp[b], __ATOMIC_RELAXED, __HIP_MEMORY_SCOPE_AGENT);
          if (f >= need) break;
          __builtin_amdgcn_s_sleep(64);
        }
        if (lane == b) fcache = f;
        asm volatile("" ::: "memory");
      }
    }
    const float* qcp = pubC + ((size_t)b * NS + s) * 3;
    float qx = __hip_atomic_load(qcp + 0, __ATOMIC_RELAXED, __HIP_MEMORY_SCOPE_AGENT);
    float qy = __hip_atomic_load(qcp + 1, __ATOMIC_RELAXED, __HIP_MEMORY_SCOPE_AGENT);
    float qz = __hip_atomic_load(qcp + 2, __ATOMIC_RELAXED, __HIP_MEMORY_SCOPE_AGENT);

    const float* xb = xyz + (size_t)b * NPTS * 3;
    float s2 = __fadd_rn(__fadd_rn(__fmul_rn(qx, qx), __fmul_rn(qy, qy)), __fmul_rn(qz, qz));

    // ---- knn pass 1: per-lane min key over 64 strided points ----
    unsigned long long mkey = 0xFFFFFFFFFFFFFFFFull;
#pragma unroll 4
    for (int j = 0; j < 64; ++j) {
      int n = j * 64 + lane;
      float px = xb[n * 3], py = xb[n * 3 + 1], pz = xb[n * 3 + 2];
      float n2 = __fadd_rn(__fadd_rn(__fmul_rn(px, px), __fmul_rn(py, py)), __fmul_rn(pz, pz));
      float dt = __fadd_rn(__fadd_rn(__fmul_rn(qx, px), __fmul_rn(qy, py)), __fmul_rn(qz, pz));
      float d  = __fadd_rn(__fsub_rn(s2, __fmul_rn(2.0f, dt)), n2);
      unsigned uu = __float_as_uint(d);
      uu ^= (0x80000000u | (unsigned)((int)uu >> 31));   // monotone float->uint
      unsigned long long key = ((unsigned long long)uu << 32) | (unsigned)n;
      mkey = key < mkey ? key : mkey;
    }

    // ---- bitonic sort of the 64 lane-minima; tau = 32nd smallest (valid upper
    //      bound on the global 32nd-smallest key since minima are 64 distinct keys) ----
    {
      unsigned mh = (unsigned)(mkey >> 32), ml2 = (unsigned)mkey;
#pragma unroll
      for (int k = 2; k <= 64; k <<= 1) {
#pragma unroll
        for (int j = k >> 1; j >= 1; j >>= 1) {
          unsigned oh = (unsigned)__shfl_xor((int)mh, j, 64);
          unsigned ol = (unsigned)__shfl_xor((int)ml2, j, 64);
          bool up = (lane & k) == 0;
          bool lower = (lane & j) == 0;
          bool omin = (oh < mh) || (oh == mh && ol < ml2);
          bool keep_o = (lower == up) ? omin : !omin;
          mh = keep_o ? oh : mh;
          ml2 = keep_o ? ol : ml2;
        }
      }
      unsigned th = (unsigned)__builtin_amdgcn_readlane((int)mh, 31);
      unsigned tl = (unsigned)__builtin_amdgcn_readlane((int)ml2, 31);
      mkey = ((unsigned long long)th << 32) | tl;   // reuse mkey as tau
    }
    const unsigned long long tau = mkey;

    // ---- knn pass 2: collect candidates <= tau (>=32 guaranteed, E~44) ----
    if (lane == 0) sh.w.cnt[wave] = 0;
    asm volatile("s_waitcnt lgkmcnt(0)" ::: "memory");
#pragma unroll 4
    for (int j = 0; j < 64; ++j) {
      int n = j * 64 + lane;
      float px = xb[n * 3], py = xb[n * 3 + 1], pz = xb[n * 3 + 2];
      float n2 = __fadd_rn(__fadd_rn(__fmul_rn(px, px), __fmul_rn(py, py)), __fmul_rn(pz, pz));
      float dt = __fadd_rn(__fadd_rn(__fmul_rn(qx, px), __fmul_rn(qy, py)), __fmul_rn(qz, pz));
      float d  = __fadd_rn(__fsub_rn(s2, __fmul_rn(2.0f, dt)), n2);
      unsigned uu = __float_as_uint(d);
      uu ^= (0x80000000u | (unsigned)((int)uu >> 31));
      unsigned long long key = ((unsigned long long)uu << 32) | (unsigned)n;
      if (key <= tau) {
        unsigned pos = atomicAdd(&sh.w.cnt[wave], 1u);
        if (pos < CAP) cand[pos] = key;
      }
    }
    asm volatile("s_waitcnt lgkmcnt(0)" ::: "memory");
    unsigned cn = sh.w.cnt[wave];
    if (cn > CAP) cn = CAP;

    // ---- exact rank-select of the 32 smallest candidates ----
    for (unsigned bb = 0; bb < cn; bb += 64) {
      unsigned i = bb + (unsigned)lane;
      unsigned long long ki = (i < cn) ? cand[i] : 0xFFFFFFFFFFFFFFFFull;
      int rank = 0;
#pragma unroll 4
      for (unsigned c2 = 0; c2 < cn; ++c2)
        rank += (cand[c2] < ki) ? 1 : 0;
      if (i < cn && rank < KNB) sh.w.nnL[wave][rank] = (int)(unsigned)(ki & 0xFFFFFFFFull);
    }
    asm volatile("s_waitcnt lgkmcnt(0)" ::: "memory");

    // ---- mlp: this wave, this query (verified MFMA path) ----
    {
      const int qi = wave;
      const float* pb = points + (size_t)b * NPTS * CPTS;
      const float* bias = sh.w.biasL;
      short* X = sh.w.X[qi];

      // X fill, vectorized: lane = r*2+h loads points[idx_r][h*32..h*32+31]
      // as 8 float4 -> 4 ds_write_b128 at cols h*32.. (16B aligned: 208B row stride)
      {
        int h = lane & 1, r = lane >> 1;
        int idx = sh.w.nnL[qi][r];
        const f32x4* src = (const f32x4*)(pb + (size_t)idx * CPTS) + h * 8;
        short8* dst = (short8*)&X[r * XSTR + h * 32];
#pragma unroll
        for (int q = 0; q < 4; ++q) {
          f32x4 v0 = src[q * 2], v1 = src[q * 2 + 1];
          short8 o;
          o[0] = f2bf(v0[0]); o[1] = f2bf(v0[1]); o[2] = f2bf(v0[2]); o[3] = f2bf(v0[3]);
          o[4] = f2bf(v1[0]); o[5] = f2bf(v1[1]); o[6] = f2bf(v1[2]); o[7] = f2bf(v1[3]);
          dst[q] = o;
        }
      }
      if (lane < 32) {   // cols 64..66 = grouped_xyz_norm
        int idx = sh.w.nnL[qi][lane];
        X[lane * XSTR + 64] = f2bf(__fsub_rn(xb[idx * 3 + 0], qx));
        X[lane * XSTR + 65] = f2bf(__fsub_rn(xb[idx * 3 + 1], qy));
        X[lane * XSTR + 66] = f2bf(__fsub_rn(xb[idx * 3 + 2], qz));
      }

      const int ml = lane & 15, quad = lane >> 4;
      const short8* Wf = (const short8*)sh.w.Wlds;

      // layer 0: M32 K96 N64
      short8 a0[2][3];
#pragma unroll
      for (int m2 = 0; m2 < 2; ++m2)
#pragma unroll
        for (int s3 = 0; s3 < 3; ++s3)
          a0[m2][s3] = *(const short8*)&X[(m2 * 16 + ml) * XSTR + s3 * 32 + quad * 8];
      f32x4 acc0[2][4];
#pragma unroll
      for (int m2 = 0; m2 < 2; ++m2)
#pragma unroll
        for (int nt = 0; nt < 4; ++nt) {
          f32x4 c = {0.f, 0.f, 0.f, 0.f};
#pragma unroll
          for (int s3 = 0; s3 < 3; ++s3)
            c = __builtin_amdgcn_mfma_f32_16x16x32_bf16(a0[m2][s3], Wf[(nt * 3 + s3) * 64 + lane], c, 0, 0, 0);
          acc0[m2][nt] = c;
        }
#pragma unroll
      for (int m2 = 0; m2 < 2; ++m2)
#pragma unroll
        for (int nt = 0; nt < 4; ++nt) {
          int ch = nt * 16 + ml;
          float bv = bias[ch];
#pragma unroll
          for (int r4 = 0; r4 < 4; ++r4) {
            float y = fmaxf(acc0[m2][nt][r4] + bv, 0.f);
            int m = quad * 4 + r4;
            int sK = ch >> 5, qq = (ch >> 3) & 3, jj = ch & 7;
            X[((m2 * 2 + sK) * 64 + qq * 16 + m) * 8 + jj] = f2bf(y);
          }
        }

      // layer 1: M32 K64 N64
      short8 a1[2][2];
#pragma unroll
      for (int m2 = 0; m2 < 2; ++m2)
#pragma unroll
        for (int sK = 0; sK < 2; ++sK)
          a1[m2][sK] = *(const short8*)&X[((m2 * 2 + sK) * 64 + lane) * 8];
      f32x4 acc1[2][4];
#pragma unroll
      for (int m2 = 0; m2 < 2; ++m2)
#pragma unroll
        for (int nt = 0; nt < 4; ++nt) {
          f32x4 c = {0.f, 0.f, 0.f, 0.f};
#pragma unroll
          for (int sK = 0; sK < 2; ++sK)
            c = __builtin_amdgcn_mfma_f32_16x16x32_bf16(a1[m2][sK], Wf[(12 + nt * 2 + sK) * 64 + lane], c, 0, 0, 0);
          acc1[m2][nt] = c;
        }
#pragma unroll
      for (int m2 = 0; m2 < 2; ++m2)
#pragma unroll
        for (int nt = 0; nt < 4; ++nt) {
          int ch = nt * 16 + ml;
          float bv = bias[64 + ch];
#pragma unroll
          for (int r4 = 0; r4 < 4; ++r4) {
            float y = fmaxf(acc1[m2][nt][r4] + bv, 0.f);
            int m = quad * 4 + r4;
            int sK = ch >> 5, qq = (ch >> 3) & 3, jj = ch & 7;
            X[((m2 * 2 + sK) * 64 + qq * 16 + m) * 8 + jj] = f2bf(y);
          }
        }

      // layer 2: M32 K64 N128 + maxpool
      short8 a2[2][2];
#pragma unroll
      for (int m2 = 0; m2 < 2; ++m2)
#pragma unroll
        for (int sK = 0; sK < 2; ++sK)
          a2[m2][sK] = *(const short8*)&X[((m2 * 2 + sK) * 64 + lane) * 8];
#pragma unroll
      for (int nt = 0; nt < 8; ++nt) {
        f32x4 c0 = {0.f, 0.f, 0.f, 0.f}, c1 = {0.f, 0.f, 0.f, 0.f};
        short8 w0f = Wf[(20 + nt * 2 + 0) * 64 + lane];
        short8 w1f = Wf[(20 + nt * 2 + 1) * 64 + lane];
        c0 = __builtin_amdgcn_mfma_f32_16x16x32_bf16(a2[0][0], w0f, c0, 0, 0, 0);
        c0 = __builtin_amdgcn_mfma_f32_16x16x32_bf16(a2[0][1], w1f, c0, 0, 0, 0);
        c1 = __builtin_amdgcn_mfma_f32_16x16x32_bf16(a2[1][0], w0f, c1, 0, 0, 0);
        c1 = __builtin_amdgcn_mfma_f32_16x16x32_bf16(a2[1][1], w1f, c1, 0, 0, 0);
        float bv = bias[128 + nt * 16 + ml];
        float m = -1.f;
#pragma unroll
        for (int r4 = 0; r4 < 4; ++r4) {
          m = fmaxf(m, fmaxf(c0[r4] + bv, 0.f));
          m = fmaxf(m, fmaxf(c1[r4] + bv, 0.f));
        }
        m = fmaxf(m, __shfl_xor(m, 16, 64));
        m = fmaxf(m, __shfl_xor(m, 32, 64));
        if (lane < 16) outp[((size_t)b * 128 + nt * 16 + lane) * NS + s] = m;
      }
    }
    }  // unit loop
  }
}

extern "C" void kernel_launch(void* const* d_in, const int* in_sizes, int n_in,
                              void* d_out, int out_size, void* d_ws, size_t ws_size,
                              hipStream_t stream) {
  const float* xyz    = (const float*)d_in[0];
  const float* points = (const float*)d_in[1];
  const float* w0  = (const float*)d_in[2];
  const float* cb0 = (const float*)d_in[3];
  const float* g0  = (const float*)d_in[4];
  const float* b0  = (const float*)d_in[5];
  const float* m0  = (const float*)d_in[6];
  const float* v0  = (const float*)d_in[7];
  const float* w1  = (const float*)d_in[8];
  const float* cb1 = (const float*)d_in[9];
  const float* g1  = (const float*)d_in[10];
  const float* b1  = (const float*)d_in[11];
  const float* m1  = (const float*)d_in[12];
  const float* v1  = (const float*)d_in[13];
  const float* w2  = (const float*)d_in[14];
  const float* cb2 = (const float*)d_in[15];
  const float* g2  = (const float*)d_in[16];
  const float* b2  = (const float*)d_in[17];
  const float* m2  = (const float*)d_in[18];
  const float* v2  = (const float*)d_in[19];

  char*  wsb    = (char*)d_ws;
  float* newxyz = (float*)d_out;                       // output 0: [16,1024,3]
  float* outp   = (float*)d_out + (size_t)NB * NS * 3; // output 1: [16,128,1024]

  hipMemsetAsync(wsb, 0, 128, stream);   // flags + counter
  fused_kernel<<<256, 512, 0, stream>>>(
      xyz, points, w0, cb0, g0, b0, m0, v0, w1, cb1, g1, b1, m1, v1,
      w2, cb2, g2, b2, m2, v2, wsb, newxyz, outp);
}

// Round 3
// 880.300 us; speedup vs baseline: 1.1678x; 1.1678x over previous
//
#include <hip/hip_runtime.h>
#include <math.h>

#pragma clang fp contract(off)

#define NPTS 4096
#define NB 16
#define NS 1024
#define KNB 32
#define CPTS 64

// ---- ws byte layout ----
#define FLAG_OFF_B  0          // 16 x u32 flags
#define CNT_OFF_B   64         // u32 work counter
#define PUBC_OFF_B  128        // fp32 pubC[16][1024][3]
#define WFRAG_ELEMS 18432
#define NUNITS      16384      // 16 batches x 1024 queries, one query per wave
#define CAP         256        // candidate buffer per wave (E[cnt]~44)
#define GRAB        2          // units per work-steal atomic (small tail)

typedef __attribute__((ext_vector_type(8))) short short8;
typedef __attribute__((ext_vector_type(4))) float f32x4;
typedef __attribute__((ext_vector_type(2))) float f32x2;

__device__ __forceinline__ short f2bf(float f) {   // RNE fp32->bf16
  unsigned u = __float_as_uint(f);
  unsigned r = (u + 0x7fffu + ((u >> 16) & 1u)) >> 16;
  return (short)r;
}

// ---------------- DPP helpers ----------------
template <int CTRL>
__device__ __forceinline__ int dppmov(int cur) {
  return __builtin_amdgcn_update_dpp(cur, cur, CTRL, 0xF, 0xF, false);
}
// f64-key max across lanes: keys are positive non-NaN doubles, so v_max_f64
// implements lexicographic (hi,lo) unsigned max == (dist_bits, ~idx) max.
template <int CTRL>
__device__ __forceinline__ double dpp_fmax64(double x) {
  int hi = __double2hiint(x), lo = __double2loint(x);
  double o = __hiloint2double(dppmov<CTRL>(hi), dppmov<CTRL>(lo));
  return fmax(x, o);
}
__device__ __forceinline__ double mkkey(float d, unsigned lo) {
  return __hiloint2double((int)__float_as_uint(d), (int)lo);
}

#define XSTR 104
__global__ __launch_bounds__(512, 2) void fused_kernel(
    const float* __restrict__ xyz, const float* __restrict__ points,
    const float* __restrict__ w0, const float* __restrict__ cb0, const float* __restrict__ g0,
    const float* __restrict__ b0, const float* __restrict__ m0, const float* __restrict__ v0,
    const float* __restrict__ w1, const float* __restrict__ cb1, const float* __restrict__ g1,
    const float* __restrict__ b1, const float* __restrict__ m1, const float* __restrict__ v1,
    const float* __restrict__ w2, const float* __restrict__ cb2, const float* __restrict__ g2,
    const float* __restrict__ b2, const float* __restrict__ m2, const float* __restrict__ v2,
    char* __restrict__ wsb, float* __restrict__ newxyz, float* __restrict__ outp) {
  struct FpsSh {
    float4 sxyz4[NPTS];                       // 64 KB
    float4 centL[NS];                         // 16 KB
    unsigned long long part[2][8];
  };
  struct WorkerSh {
    short Wlds[WFRAG_ELEMS];                  // 36 KB
    short X[8][32 * XSTR];                    // 52 KB (per-wave MLP tile)
    unsigned long long cand[8][CAP];          // 16 KB (per-wave knn candidates)
    int nnL[8][KNB];                          // 1 KB
    float biasL[256];                         // 1 KB
    unsigned cnt[8];
  };
  __shared__ union { FpsSh f; WorkerSh w; } sh;

  const int t = threadIdx.x;
  const int lane = t & 63;
  const int wave = t >> 6;
  unsigned* flagp = (unsigned*)(wsb + FLAG_OFF_B);
  unsigned* cntp  = (unsigned*)(wsb + CNT_OFF_B);
  float* pubC = (float*)(wsb + PUBC_OFF_B);

  if (blockIdx.x < NB) {
    // ================= FPS: f64-key fused (value,index) argmax reduce ==========
    const int b = blockIdx.x;
    const float* xb = xyz + (size_t)b * NPTS * 3;
    float* outb = newxyz + (size_t)b * NS * 3;

    for (int i = t; i < NPTS; i += 512)
      sh.f.sxyz4[i] = make_float4(xb[i * 3 + 0], xb[i * 3 + 1], xb[i * 3 + 2], 0.f);

    // point pairs (j even -> .x, j odd -> .y), packed for v_pk_* f32 math
    f32x2 px2[4], py2[4], pz2[4], d2[4];
    unsigned lo8[8];
#pragma unroll
    for (int j = 0; j < 8; ++j) lo8[j] = ~(unsigned)(t + 512 * j);
#pragma unroll
    for (int j2 = 0; j2 < 4; ++j2) {
      int n0 = t + 512 * (2 * j2), n1 = t + 512 * (2 * j2 + 1);
      px2[j2].x = xb[n0 * 3 + 0]; px2[j2].y = xb[n1 * 3 + 0];
      py2[j2].x = xb[n0 * 3 + 1]; py2[j2].y = xb[n1 * 3 + 1];
      pz2[j2].x = xb[n0 * 3 + 2]; pz2[j2].y = xb[n1 * 3 + 2];
      d2[j2].x = 1e10f; d2[j2].y = 1e10f;
    }
    __syncthreads();
    float cx = sh.f.sxyz4[0].x, cy = sh.f.sxyz4[0].y, cz = sh.f.sxyz4[0].z;
    if (t == 0) sh.f.centL[0] = sh.f.sxyz4[0];

    for (int it = 1; it < NS; ++it) {
      const int buf = it & 1;
      // distance update: exact (x-c)*(x-c) sums with the reference's association;
      // fp contract(off) guarantees no FMA fusion; pk ops are bit-identical IEEE.
      f32x2 cax; cax.x = cx; cax.y = cx;
      f32x2 cay; cay.x = cy; cay.y = cy;
      f32x2 caz; caz.x = cz; caz.y = cz;
      double kk[8];
#pragma unroll
      for (int j2 = 0; j2 < 4; ++j2) {
        f32x2 dx = px2[j2] - cax;
        f32x2 dy = py2[j2] - cay;
        f32x2 dz = pz2[j2] - caz;
        f32x2 dd = (dx * dx + dy * dy) + dz * dz;
        f32x2 dv = d2[j2];
        dv.x = fminf(dv.x, dd.x);
        dv.y = fminf(dv.y, dd.y);
        d2[j2] = dv;
        kk[2 * j2]     = mkkey(dv.x, lo8[2 * j2]);
        kk[2 * j2 + 1] = mkkey(dv.y, lo8[2 * j2 + 1]);
      }
      // per-lane 8->1 key max (tie -> larger ~idx == lower idx), then 6-stage DPP
      double km = fmax(fmax(fmax(kk[0], kk[1]), fmax(kk[2], kk[3])),
                       fmax(fmax(kk[4], kk[5]), fmax(kk[6], kk[7])));
      km = dpp_fmax64<0xB1>(km);  km = dpp_fmax64<0x4E>(km);  km = dpp_fmax64<0x141>(km);
      km = dpp_fmax64<0x140>(km); km = dpp_fmax64<0x142>(km); km = dpp_fmax64<0x143>(km);
      if (lane == 63)
        sh.f.part[buf][wave] = (unsigned long long)__double_as_longlong(km);
      __syncthreads();
      // merge 8 wave partials: slot read + 3-stage DPP f64 max (all lanes get winner)
      double kw = __longlong_as_double((long long)sh.f.part[buf][lane & 7]);
      kw = dpp_fmax64<0xB1>(kw); kw = dpp_fmax64<0x4E>(kw); kw = dpp_fmax64<0x141>(kw);
      int bi = (int)(~(unsigned)__double2loint(kw)) & 4095;
      float4 c4 = sh.f.sxyz4[bi];
      cx = c4.x; cy = c4.y; cz = c4.z;
      if (t == 0) sh.f.centL[it] = c4;
      // publish: drain prior chunk's pubC stores (long done), relaxed flag store,
      // then store this chunk's centroids (bypassing).
      if ((it & 31) == 31 && wave == 0) {
        if (lane == 0) {
          asm volatile("s_waitcnt vmcnt(0)" ::: "memory");
          __hip_atomic_store(&flagp[b], (unsigned)(it - 31), __ATOMIC_RELAXED, __HIP_MEMORY_SCOPE_AGENT);
        }
        if (lane < 32) {
          int ci = it - 31 + lane;
          float4 cc = sh.f.centL[ci];
          float* dst = pubC + ((size_t)b * NS + ci) * 3;
          __hip_atomic_store(dst + 0, cc.x, __ATOMIC_RELAXED, __HIP_MEMORY_SCOPE_AGENT);
          __hip_atomic_store(dst + 1, cc.y, __ATOMIC_RELAXED, __HIP_MEMORY_SCOPE_AGENT);
          __hip_atomic_store(dst + 2, cc.z, __ATOMIC_RELAXED, __HIP_MEMORY_SCOPE_AGENT);
        }
      }
    }
    // final flag (drain last chunk's stores once)
    if (wave == 0 && lane == 0) {
      asm volatile("s_waitcnt vmcnt(0)" ::: "memory");
      __hip_atomic_store(&flagp[b], (unsigned)NS, __ATOMIC_RELAXED, __HIP_MEMORY_SCOPE_AGENT);
    }
    __syncthreads();
    const float* cf = (const float*)sh.f.centL;
    for (int i = t; i < NS * 3; i += 512) {
      int p = i / 3, c = i - p * 3;
      outb[i] = cf[p * 4 + c];
    }
  }

  // ================= worker phase =================
  // One query per WAVE; GRAB units per steal. All polls RELAXED + per-wave
  // lane-indexed flag cache (lane i caches flag[i]) -> ~zero poll traffic.
  __syncthreads();
  // BN-folded bf16 weight fragments + biases into LDS.
  // K-column permutation for layer 0: X cols 0..63 = points[0..63] (w0 k'=c+3),
  // cols 64..66 = xyz_norm (w0 k'=c-64), cols 67..95 = zero weights.
  for (int i = t; i < WFRAG_ELEMS; i += 512) {
    int g = i >> 9, ln = (i >> 3) & 63, j = i & 7;
    int l, nt, s;
    if (g < 12)      { l = 0; nt = g / 3;  s = g % 3; }
    else if (g < 20) { l = 1; int gg = g - 12; nt = gg >> 1; s = gg & 1; }
    else             { l = 2; int gg = g - 20; nt = gg >> 1; s = gg & 1; }
    int n = nt * 16 + (ln & 15);
    int k = s * 32 + ((ln >> 4) << 3) + j;
    float val = 0.f;
    if (l == 0) {
      float sc = g0[n] / sqrtf(v0[n] + 1e-5f);
      if (k < 64)      val = w0[n * 67 + (k + 3)] * sc;
      else if (k < 67) val = w0[n * 67 + (k - 64)] * sc;
    }
    else if (l == 1) { val = w1[n * 64 + k] * (g1[n] / sqrtf(v1[n] + 1e-5f)); }
    else { val = w2[n * 64 + k] * (g2[n] / sqrtf(v2[n] + 1e-5f)); }
    sh.w.Wlds[i] = f2bf(val);
  }
  if (t < 256) {
    int o = t;
    float bv;
    if (o < 64)       { float sc = g0[o] / sqrtf(v0[o] + 1e-5f); bv = (cb0[o] - m0[o]) * sc + b0[o]; }
    else if (o < 128) { int c = o - 64;  float sc = g1[c] / sqrtf(v1[c] + 1e-5f); bv = (cb1[c] - m1[c]) * sc + b1[c]; }
    else              { int c = o - 128; float sc = g2[c] / sqrtf(v2[c] + 1e-5f); bv = (cb2[c] - m2[c]) * sc + b2[c]; }
    sh.w.biasL[o] = bv;
  }
  __syncthreads();   // weights/bias visible to all waves before any wave starts

  unsigned long long* cand = sh.w.cand[wave];
  // one-time zero of this wave's X tile (cols 67..95 stay zero; zero-weight cols
  // must not read uninitialized LDS that could encode NaN/Inf)
  for (int i = lane; i < (32 * XSTR) / 2; i += 64) ((int*)sh.w.X[wave])[i] = 0;

  unsigned fcache = 0;   // lane i holds last-seen flag[i] (i<16)

  for (;;) {
    unsigned base = 0;
    if (lane == 0) base = atomicAdd(cntp, (unsigned)GRAB);
    base = (unsigned)__builtin_amdgcn_readfirstlane((int)base);
    if (base >= NUNITS) break;
    unsigned uend = base + GRAB;
    if (uend > NUNITS) uend = NUNITS;

    for (unsigned u = base; u < uend; ++u) {
    const int b = (int)(u & 15u);
    const int s = (int)(u >> 4);

    // producer wait: cached-flag fast path, relaxed polls otherwise
    {
      unsigned need = (unsigned)s + 1u;
      unsigned have = (unsigned)__shfl((int)fcache, b, 64);
      if (have < need) {
        unsigned f;
        for (;;) {
          f = __hip_atomic_load(&flagp[b], __ATOMIC_RELAXED, __HIP_MEMORY_SCOPE_AGENT);
          if (f >= need) break;
          __builtin_amdgcn_s_sleep(64);
        }
        if (lane == b) fcache = f;
        asm volatile("" ::: "memory");
      }
    }
    const float* qcp = pubC + ((size_t)b * NS + s) * 3;
    float qx = __hip_atomic_load(qcp + 0, __ATOMIC_RELAXED, __HIP_MEMORY_SCOPE_AGENT);
    float qy = __hip_atomic_load(qcp + 1, __ATOMIC_RELAXED, __HIP_MEMORY_SCOPE_AGENT);
    float qz = __hip_atomic_load(qcp + 2, __ATOMIC_RELAXED, __HIP_MEMORY_SCOPE_AGENT);

    const float* xb = xyz + (size_t)b * NPTS * 3;
    float s2 = __fadd_rn(__fadd_rn(__fmul_rn(qx, qx), __fmul_rn(qy, qy)), __fmul_rn(qz, qz));

    // ---- knn pass 1: per-lane min key over 64 strided points ----
    unsigned long long mkey = 0xFFFFFFFFFFFFFFFFull;
#pragma unroll 4
    for (int j = 0; j < 64; ++j) {
      int n = j * 64 + lane;
      float px = xb[n * 3], py = xb[n * 3 + 1], pz = xb[n * 3 + 2];
      float n2 = __fadd_rn(__fadd_rn(__fmul_rn(px, px), __fmul_rn(py, py)), __fmul_rn(pz, pz));
      float dt = __fadd_rn(__fadd_rn(__fmul_rn(qx, px), __fmul_rn(qy, py)), __fmul_rn(qz, pz));
      float d  = __fadd_rn(__fsub_rn(s2, __fmul_rn(2.0f, dt)), n2);
      unsigned uu = __float_as_uint(d);
      uu ^= (0x80000000u | (unsigned)((int)uu >> 31));   // monotone float->uint
      unsigned long long key = ((unsigned long long)uu << 32) | (unsigned)n;
      mkey = key < mkey ? key : mkey;
    }

    // ---- bitonic sort of the 64 lane-minima; tau = 32nd smallest (valid upper
    //      bound on the global 32nd-smallest key since minima are 64 distinct keys) ----
    {
      unsigned mh = (unsigned)(mkey >> 32), ml2 = (unsigned)mkey;
#pragma unroll
      for (int k = 2; k <= 64; k <<= 1) {
#pragma unroll
        for (int j = k >> 1; j >= 1; j >>= 1) {
          unsigned oh = (unsigned)__shfl_xor((int)mh, j, 64);
          unsigned ol = (unsigned)__shfl_xor((int)ml2, j, 64);
          bool up = (lane & k) == 0;
          bool lower = (lane & j) == 0;
          bool omin = (oh < mh) || (oh == mh && ol < ml2);
          bool keep_o = (lower == up) ? omin : !omin;
          mh = keep_o ? oh : mh;
          ml2 = keep_o ? ol : ml2;
        }
      }
      unsigned th = (unsigned)__builtin_amdgcn_readlane((int)mh, 31);
      unsigned tl = (unsigned)__builtin_amdgcn_readlane((int)ml2, 31);
      mkey = ((unsigned long long)th << 32) | tl;   // reuse mkey as tau
    }
    const unsigned long long tau = mkey;

    // ---- knn pass 2: collect candidates <= tau (>=32 guaranteed, E~44) ----
    if (lane == 0) sh.w.cnt[wave] = 0;
    asm volatile("s_waitcnt lgkmcnt(0)" ::: "memory");
#pragma unroll 4
    for (int j = 0; j < 64; ++j) {
      int n = j * 64 + lane;
      float px = xb[n * 3], py = xb[n * 3 + 1], pz = xb[n * 3 + 2];
      float n2 = __fadd_rn(__fadd_rn(__fmul_rn(px, px), __fmul_rn(py, py)), __fmul_rn(pz, pz));
      float dt = __fadd_rn(__fadd_rn(__fmul_rn(qx, px), __fmul_rn(qy, py)), __fmul_rn(qz, pz));
      float d  = __fadd_rn(__fsub_rn(s2, __fmul_rn(2.0f, dt)), n2);
      unsigned uu = __float_as_uint(d);
      uu ^= (0x80000000u | (unsigned)((int)uu >> 31));
      unsigned long long key = ((unsigned long long)uu << 32) | (unsigned)n;
      if (key <= tau) {
        unsigned pos = atomicAdd(&sh.w.cnt[wave], 1u);
        if (pos < CAP) cand[pos] = key;
      }
    }
    asm volatile("s_waitcnt lgkmcnt(0)" ::: "memory");
    unsigned cn = sh.w.cnt[wave];
    if (cn > CAP) cn = CAP;

    // ---- exact rank-select of the 32 smallest candidates ----
    for (unsigned bb = 0; bb < cn; bb += 64) {
      unsigned i = bb + (unsigned)lane;
      unsigned long long ki = (i < cn) ? cand[i] : 0xFFFFFFFFFFFFFFFFull;
      int rank = 0;
#pragma unroll 4
      for (unsigned c2 = 0; c2 < cn; ++c2)
        rank += (cand[c2] < ki) ? 1 : 0;
      if (i < cn && rank < KNB) sh.w.nnL[wave][rank] = (int)(unsigned)(ki & 0xFFFFFFFFull);
    }
    asm volatile("s_waitcnt lgkmcnt(0)" ::: "memory");

    // ---- mlp: this wave, this query (verified MFMA path) ----
    {
      const int qi = wave;
      const float* pb = points + (size_t)b * NPTS * CPTS;
      const float* bias = sh.w.biasL;
      short* X = sh.w.X[qi];

      // X fill, vectorized: lane = r*2+h loads points[idx_r][h*32..h*32+31]
      // as 8 float4 -> 4 ds_write_b128 at cols h*32.. (16B aligned: 208B row stride)
      {
        int h = lane & 1, r = lane >> 1;
        int idx = sh.w.nnL[qi][r];
        const f32x4* src = (const f32x4*)(pb + (size_t)idx * CPTS) + h * 8;
        short8* dst = (short8*)&X[r * XSTR + h * 32];
#pragma unroll
        for (int q = 0; q < 4; ++q) {
          f32x4 v0 = src[q * 2], v1 = src[q * 2 + 1];
          short8 o;
          o[0] = f2bf(v0[0]); o[1] = f2bf(v0[1]); o[2] = f2bf(v0[2]); o[3] = f2bf(v0[3]);
          o[4] = f2bf(v1[0]); o[5] = f2bf(v1[1]); o[6] = f2bf(v1[2]); o[7] = f2bf(v1[3]);
          dst[q] = o;
        }
      }
      if (lane < 32) {   // cols 64..66 = grouped_xyz_norm
        int idx = sh.w.nnL[qi][lane];
        X[lane * XSTR + 64] = f2bf(__fsub_rn(xb[idx * 3 + 0], qx));
        X[lane * XSTR + 65] = f2bf(__fsub_rn(xb[idx * 3 + 1], qy));
        X[lane * XSTR + 66] = f2bf(__fsub_rn(xb[idx * 3 + 2], qz));
      }

      const int ml = lane & 15, quad = lane >> 4;
      const short8* Wf = (const short8*)sh.w.Wlds;

      // layer 0: M32 K96 N64
      short8 a0[2][3];
#pragma unroll
      for (int m2 = 0; m2 < 2; ++m2)
#pragma unroll
        for (int s3 = 0; s3 < 3; ++s3)
          a0[m2][s3] = *(const short8*)&X[(m2 * 16 + ml) * XSTR + s3 * 32 + quad * 8];
      f32x4 acc0[2][4];
#pragma unroll
      for (int m2 = 0; m2 < 2; ++m2)
#pragma unroll
        for (int nt = 0; nt < 4; ++nt) {
          f32x4 c = {0.f, 0.f, 0.f, 0.f};
#pragma unroll
          for (int s3 = 0; s3 < 3; ++s3)
            c = __builtin_amdgcn_mfma_f32_16x16x32_bf16(a0[m2][s3], Wf[(nt * 3 + s3) * 64 + lane], c, 0, 0, 0);
          acc0[m2][nt] = c;
        }
#pragma unroll
      for (int m2 = 0; m2 < 2; ++m2)
#pragma unroll
        for (int nt = 0; nt < 4; ++nt) {
          int ch = nt * 16 + ml;
          float bv = bias[ch];
#pragma unroll
          for (int r4 = 0; r4 < 4; ++r4) {
            float y = fmaxf(acc0[m2][nt][r4] + bv, 0.f);
            int m = quad * 4 + r4;
            int sK = ch >> 5, qq = (ch >> 3) & 3, jj = ch & 7;
            X[((m2 * 2 + sK) * 64 + qq * 16 + m) * 8 + jj] = f2bf(y);
          }
        }

      // layer 1: M32 K64 N64
      short8 a1[2][2];
#pragma unroll
      for (int m2 = 0; m2 < 2; ++m2)
#pragma unroll
        for (int sK = 0; sK < 2; ++sK)
          a1[m2][sK] = *(const short8*)&X[((m2 * 2 + sK) * 64 + lane) * 8];
      f32x4 acc1[2][4];
#pragma unroll
      for (int m2 = 0; m2 < 2; ++m2)
#pragma unroll
        for (int nt = 0; nt < 4; ++nt) {
          f32x4 c = {0.f, 0.f, 0.f, 0.f};
#pragma unroll
          for (int sK = 0; sK < 2; ++sK)
            c = __builtin_amdgcn_mfma_f32_16x16x32_bf16(a1[m2][sK], Wf[(12 + nt * 2 + sK) * 64 + lane], c, 0, 0, 0);
          acc1[m2][nt] = c;
        }
#pragma unroll
      for (int m2 = 0; m2 < 2; ++m2)
#pragma unroll
        for (int nt = 0; nt < 4; ++nt) {
          int ch = nt * 16 + ml;
          float bv = bias[64 + ch];
#pragma unroll
          for (int r4 = 0; r4 < 4; ++r4) {
            float y = fmaxf(acc1[m2][nt][r4] + bv, 0.f);
            int m = quad * 4 + r4;
            int sK = ch >> 5, qq = (ch >> 3) & 3, jj = ch & 7;
            X[((m2 * 2 + sK) * 64 + qq * 16 + m) * 8 + jj] = f2bf(y);
          }
        }

      // layer 2: M32 K64 N128 + maxpool
      short8 a2[2][2];
#pragma unroll
      for (int m2 = 0; m2 < 2; ++m2)
#pragma unroll
        for (int sK = 0; sK < 2; ++sK)
          a2[m2][sK] = *(const short8*)&X[((m2 * 2 + sK) * 64 + lane) * 8];
#pragma unroll
      for (int nt = 0; nt < 8; ++nt) {
        f32x4 c0 = {0.f, 0.f, 0.f, 0.f}, c1 = {0.f, 0.f, 0.f, 0.f};
        short8 w0f = Wf[(20 + nt * 2 + 0) * 64 + lane];
        short8 w1f = Wf[(20 + nt * 2 + 1) * 64 + lane];
        c0 = __builtin_amdgcn_mfma_f32_16x16x32_bf16(a2[0][0], w0f, c0, 0, 0, 0);
        c0 = __builtin_amdgcn_mfma_f32_16x16x32_bf16(a2[0][1], w1f, c0, 0, 0, 0);
        c1 = __builtin_amdgcn_mfma_f32_16x16x32_bf16(a2[1][0], w0f, c1, 0, 0, 0);
        c1 = __builtin_amdgcn_mfma_f32_16x16x32_bf16(a2[1][1], w1f, c1, 0, 0, 0);
        float bv = bias[128 + nt * 16 + ml];
        float m = -1.f;
#pragma unroll
        for (int r4 = 0; r4 < 4; ++r4) {
          m = fmaxf(m, fmaxf(c0[r4] + bv, 0.f));
          m = fmaxf(m, fmaxf(c1[r4] + bv, 0.f));
        }
        m = fmaxf(m, __shfl_xor(m, 16, 64));
        m = fmaxf(m, __shfl_xor(m, 32, 64));
        if (lane < 16) outp[((size_t)b * 128 + nt * 16 + lane) * NS + s] = m;
      }
    }
    }  // unit loop
  }
}

extern "C" void kernel_launch(void* const* d_in, const int* in_sizes, int n_in,
                              void* d_out, int out_size, void* d_ws, size_t ws_size,
                              hipStream_t stream) {
  const float* xyz    = (const float*)d_in[0];
  const float* points = (const float*)d_in[1];
  const float* w0  = (const float*)d_in[2];
  const float* cb0 = (const float*)d_in[3];
  const float* g0  = (const float*)d_in[4];
  const float* b0  = (const float*)d_in[5];
  const float* m0  = (const float*)d_in[6];
  const float* v0  = (const float*)d_in[7];
  const float* w1  = (const float*)d_in[8];
  const float* cb1 = (const float*)d_in[9];
  const float* g1  = (const float*)d_in[10];
  const float* b1  = (const float*)d_in[11];
  const float* m1  = (const float*)d_in[12];
  const float* v1  = (const float*)d_in[13];
  const float* w2  = (const float*)d_in[14];
  const float* cb2 = (const float*)d_in[15];
  const float* g2  = (const float*)d_in[16];
  const float* b2  = (const float*)d_in[17];
  const float* m2  = (const float*)d_in[18];
  const float* v2  = (const float*)d_in[19];

  char*  wsb    = (char*)d_ws;
  float* newxyz = (float*)d_out;                       // output 0: [16,1024,3]
  float* outp   = (float*)d_out + (size_t)NB * NS * 3; // output 1: [16,128,1024]

  hipMemsetAsync(wsb, 0, 128, stream);   // flags + counter
  fused_kernel<<<256, 512, 0, stream>>>(
      xyz, points, w0, cb0, g0, b0, m0, v0, w1, cb1, g1, b1, m1, v1,
      w2, cb2, g2, b2, m2, v2, wsb, newxyz, outp);
}